// Round 6
// baseline (421.122 us; speedup 1.0000x reference)
//
#include <hip/hip_runtime.h>
#include <hip/hip_bf16.h>

typedef __bf16 bf16;
typedef __bf16 bf16x8 __attribute__((ext_vector_type(8)));
typedef float f32x4 __attribute__((ext_vector_type(4)));
typedef float f32x16 __attribute__((ext_vector_type(16)));
typedef unsigned int u32x4 __attribute__((ext_vector_type(4)));

#define EXP2(x) __builtin_amdgcn_exp2f(x)

static __device__ __forceinline__ f32x4 mfma16(bf16x8 a, bf16x8 b, f32x4 c) {
    return __builtin_amdgcn_mfma_f32_16x16x32_bf16(a, b, c, 0, 0, 0);
}
static __device__ __forceinline__ f32x16 mfma32(bf16x8 a, bf16x8 b, f32x16 c) {
    return __builtin_amdgcn_mfma_f32_32x32x16_bf16(a, b, c, 0, 0, 0);
}
static __device__ __forceinline__ unsigned cvt_pk(float lo, float hi) {
    unsigned r;
    asm("v_cvt_pk_bf16_f32 %0, %1, %2" : "=v"(r) : "v"(lo), "v"(hi));
    return r;
}
static __device__ __forceinline__ void perm32swap(unsigned &a, unsigned &b) {
    asm("v_permlane32_swap_b32 %0, %1" : "+v"(a), "+v"(b));
}

// ---------------- Kernel 1: weight convert (+ fold softmax scale*log2e into Q rows) ----
__global__ __launch_bounds__(256) void prep_w_kernel(const float* __restrict__ qkv_w,
                                                     const float* __restrict__ proj_w,
                                                     bf16* __restrict__ wqkv,
                                                     bf16* __restrict__ wproj) {
    int idx = blockIdx.x * 256 + threadIdx.x;
    const float QSCALE = 0.17677669529663689f * 1.4426950408889634f; // hd^-0.5 * log2(e)
    if (idx < 768 * 256) {
        float v = qkv_w[idx];
        if (idx < 256 * 256) v *= QSCALE;   // rows o<256 are the Q projection
        wqkv[idx] = (bf16)v;
    } else {
        int j = idx - 768 * 256;
        wproj[j] = (bf16)proj_w[j];
    }
}

// ---------------- Kernel 2: x [2][256][4096] f32 -> xT [2][4096][256] bf16 ------------
// 64c x 64n tile; f32x4 coalesced loads, LDS transpose, bf16x8 16B stores.
__global__ __launch_bounds__(256) void transpose_x_kernel(const float* __restrict__ x,
                                                          bf16* __restrict__ xT) {
    __shared__ float tile[64][68];
    int b = blockIdx.z, cb = blockIdx.y * 64, nb = blockIdx.x * 64;
    int t = threadIdx.x;
    int j = t & 15, rc = t >> 4;     // load: rows c = rc+16i, cols n = j*4..j*4+3
    const float* src = x + ((size_t)b * 256 + cb) * 4096 + nb;
#pragma unroll
    for (int i = 0; i < 4; i++) {
        f32x4 v = *(const f32x4*)(src + (size_t)(rc + i * 16) * 4096 + j * 4);
        *(f32x4*)&tile[rc + i * 16][j * 4] = v;
    }
    __syncthreads();
    int n = t >> 2;                  // write: row n, c-octet (t&3) + 4i
    bf16* dst = xT + ((size_t)b * 4096 + nb + n) * 256 + cb;
#pragma unroll
    for (int i = 0; i < 2; i++) {
        int c0 = ((t & 3) + i * 4) * 8;
        bf16x8 v;
#pragma unroll
        for (int jj = 0; jj < 8; jj++) v[jj] = (bf16)tile[c0 + jj][n];
        *(bf16x8*)(dst + c0) = v;
    }
}

// ---------------- Kernel 3: QKV GEMM.  D[n][o] = xT[n][c] * wqkv[o][c]^T --------------
// Tile 64n x 128o, 4 waves (2x2), wave 32n x 64o. Q written [bh][n][32];
// K,V written MFMA-FRAGMENT-PACKED: Kp/Vp [bh][kt][which][lane][8].
__global__ __launch_bounds__(256) void qkv_gemm_kernel(const bf16* __restrict__ xT,
                                                       const bf16* __restrict__ w,
                                                       bf16* __restrict__ Q,
                                                       bf16* __restrict__ Kp,
                                                       bf16* __restrict__ Vp) {
    int b = blockIdx.z;
    int nb = blockIdx.x * 64, ob = blockIdx.y * 128;
    int t = threadIdx.x, wid = t >> 6, lane = t & 63;
    int l15 = lane & 15, g = lane >> 4;
    int wr = wid >> 1, wc = wid & 1;
    const bf16* xrow = xT + ((size_t)b * 4096 + nb + wr * 32 + l15) * 256 + g * 8;
    const bf16* wrow = w + (size_t)(ob + wc * 64 + l15) * 256 + g * 8;
    f32x4 acc[2][4] = {};
    for (int k0 = 0; k0 < 256; k0 += 32) {
        bf16x8 a[2], bb[4];
#pragma unroll
        for (int rt = 0; rt < 2; rt++) a[rt] = *(const bf16x8*)(xrow + rt * 16 * 256 + k0);
#pragma unroll
        for (int cg = 0; cg < 4; cg++) bb[cg] = *(const bf16x8*)(wrow + cg * 16 * 256 + k0);
#pragma unroll
        for (int rt = 0; rt < 2; rt++)
#pragma unroll
            for (int cg = 0; cg < 4; cg++)
                acc[rt][cg] = mfma16(a[rt], bb[cg], acc[rt][cg]);
    }
#pragma unroll
    for (int rt = 0; rt < 2; rt++) {
#pragma unroll
        for (int cg = 0; cg < 4; cg++) {
            int o = ob + wc * 64 + cg * 16 + l15;
            int tsel = o >> 8;           // 0=Q 1=K 2=V
            int h = (o >> 5) & 7;
            int d = o & 31;
            int n0 = nb + wr * 32 + rt * 16 + g * 4;
            size_t bhbase = ((size_t)b * 8 + h) * 131072;
            if (tsel == 0) {
#pragma unroll
                for (int i = 0; i < 4; i++)
                    Q[(((size_t)b * 8 + h) * 4096 + n0 + i) * 32 + d] = (bf16)acc[rt][cg][i];
            } else if (tsel == 1) {
                // K fragment pack: rows n, elems d. which = d>>4, hi2 = (d>>3)&1
                int kt = n0 >> 5;
                int which = d >> 4, hi2 = (d >> 3) & 1, j = d & 7;
                size_t base = bhbase + (size_t)(((kt * 2 + which) * 64 + hi2 * 32) * 8 + j);
#pragma unroll
                for (int i = 0; i < 4; i++) {
                    int r5 = (n0 + i) & 31;
                    Kp[base + r5 * 8] = (bf16)acc[rt][cg][i];
                }
            } else {
                // V^T fragment pack: rows d, elems k (=n). which = kk>>4, hi2 = (kk>>3)&1
                int kt = n0 >> 5, kk0 = n0 & 31;
                int which = kk0 >> 4, hi2 = (kk0 >> 3) & 1, j0 = kk0 & 7;
                unsigned p0 = cvt_pk(acc[rt][cg][0], acc[rt][cg][1]);
                unsigned p1 = cvt_pk(acc[rt][cg][2], acc[rt][cg][3]);
                uint2 wv; wv.x = p0; wv.y = p1;
                *(uint2*)(Vp + bhbase + (size_t)(((kt * 2 + which) * 64 + hi2 * 32 + d) * 8 + j0)) = wv;
            }
        }
    }
}

// ---------------- Kernel 4: flash attention, packed + XCD-swizzled + k-split 4 --------
// 1-D grid of 1024 blocks: bh = (w&7)+8*((w>>3)&1) (XCD-local), qblk = w>>4 (0..63).
// 512 thr = 8 waves: (z = wid>>1 in 0..3, wq = wid&1). Per wave: 32 q-rows, quarter
// k-range (1024), KVBLK=32, all loads base+lane*16B. Fixed-base softmax; l via
// ones-MFMA; K/V double-buffered in regs, 2x unroll. 3-partial LDS combine at end.
// VGPR <= 64 via launch_bounds(512,8) -> 8 waves/SIMD (full occupancy).
#define PACK(stv, B, OUT) {                                  \
    unsigned _x01 = cvt_pk(stv[B + 0], stv[B + 1]);          \
    unsigned _x23 = cvt_pk(stv[B + 2], stv[B + 3]);          \
    unsigned _y01 = cvt_pk(stv[B + 4], stv[B + 5]);          \
    unsigned _y23 = cvt_pk(stv[B + 6], stv[B + 7]);          \
    perm32swap(_x01, _y01);                                  \
    perm32swap(_x23, _y23);                                  \
    u32x4 _w = {_x01, _x23, _y01, _y23};                     \
    OUT = __builtin_bit_cast(bf16x8, _w); }

#define BODY(KF0, KF1, VF0, VF1) {                           \
    f32x16 st = mfma32(KF0, qf0, ZERO16);                    \
    st = mfma32(KF1, qf1, st);                               \
    _Pragma("unroll")                                        \
    for (int r = 0; r < 16; r++) st[r] = EXP2(st[r]);        \
    bf16x8 pb0, pb1;                                         \
    PACK(st, 0, pb0);                                        \
    PACK(st, 8, pb1);                                        \
    __builtin_amdgcn_s_setprio(1);                           \
    rs = mfma32(ones, pb0, rs);                              \
    o_acc = mfma32(VF0, pb0, o_acc);                         \
    rs = mfma32(ones, pb1, rs);                              \
    o_acc = mfma32(VF1, pb1, o_acc);                         \
    __builtin_amdgcn_s_setprio(0); }

__global__ __launch_bounds__(512, 8) void attn_kernel(const bf16* __restrict__ Q,
                                                      const bf16* __restrict__ Kp,
                                                      const bf16* __restrict__ Vp,
                                                      bf16* __restrict__ attT) {
    __shared__ __align__(16) float ldsO[3][2][64][20];   // ~30 KB
    __shared__ float ldsL[3][2][32];

    const int w = blockIdx.x;
    const int bh = (w & 7) + 8 * ((w >> 3) & 1);   // XCD w&7 -> bh {w&7, w&7+8}
    const int qblk = w >> 4;                       // 0..63
    const int t = threadIdx.x;
    const int wid = t >> 6, lane = t & 63;
    const int z = wid >> 1, wq = wid & 1;          // z: k-quarter, wq: q-subtile
    const int l31 = lane & 31, hi = lane >> 5;
    const int q0 = qblk * 64 + wq * 32;

    const bf16* __restrict__ Qb = Q + (size_t)bh * 4096 * 32;
    const bf16* kptr = Kp + (size_t)bh * 131072 + (size_t)z * 32768 + lane * 8;
    const bf16* vptr = Vp + (size_t)bh * 131072 + (size_t)z * 32768 + lane * 8;

    // Q B-frags (col = q = l31), elements d = ks*16 + hi*8 + j
    bf16x8 qf0 = *(const bf16x8*)(Qb + (size_t)(q0 + l31) * 32 + hi * 8);
    bf16x8 qf1 = *(const bf16x8*)(Qb + (size_t)(q0 + l31) * 32 + 16 + hi * 8);

    bf16x8 ones;
#pragma unroll
    for (int j = 0; j < 8; j++) ones[j] = (bf16)1.0f;
    const f32x16 ZERO16 = {};

    f32x16 o_acc = {};
    f32x16 rs = {};

    bf16x8 kf0 = *(const bf16x8*)(kptr);
    bf16x8 kf1 = *(const bf16x8*)(kptr + 512);
    bf16x8 vf0 = *(const bf16x8*)(vptr);
    bf16x8 vf1 = *(const bf16x8*)(vptr + 512);

    for (int it = 0; it < 32; it += 2) {
        // prefetch tile it+1
        bf16x8 kn0 = *(const bf16x8*)(kptr + 1024);
        bf16x8 kn1 = *(const bf16x8*)(kptr + 1536);
        bf16x8 vn0 = *(const bf16x8*)(vptr + 1024);
        bf16x8 vn1 = *(const bf16x8*)(vptr + 1536);
        BODY(kf0, kf1, vf0, vf1);
        // prefetch tile it+2 (tail overrun lands in adjacent ws buffers: harmless)
        kf0 = *(const bf16x8*)(kptr + 2048);
        kf1 = *(const bf16x8*)(kptr + 2560);
        vf0 = *(const bf16x8*)(vptr + 2048);
        vf1 = *(const bf16x8*)(vptr + 2560);
        kptr += 2048; vptr += 2048;
        BODY(kn0, kn1, vn0, vn1);
    }

    // ---- combine 4 k-quarter partials via LDS, write attT [b][n][256] ----
    if (z != 0) {
#pragma unroll
        for (int g = 0; g < 4; g++) {
            f32x4 wv = {o_acc[4 * g + 0], o_acc[4 * g + 1], o_acc[4 * g + 2], o_acc[4 * g + 3]};
            *(f32x4*)&ldsO[z - 1][wq][lane][4 * g] = wv;
        }
        if (hi == 0) ldsL[z - 1][wq][l31] = rs[0];
    }
    __syncthreads();
    if (z == 0) {
        float lsum = rs[0] + ldsL[0][wq][l31] + ldsL[1][wq][l31] + ldsL[2][wq][l31];
        float inv = __builtin_amdgcn_rcpf(lsum);
        const int b = bh >> 3, h = bh & 7;
        bf16* orow = attT + ((size_t)b * 4096 + q0 + l31) * 256 + h * 32 + 4 * hi;
#pragma unroll
        for (int g = 0; g < 4; g++) {
            f32x4 p0 = *(const f32x4*)&ldsO[0][wq][lane][4 * g];
            f32x4 p1 = *(const f32x4*)&ldsO[1][wq][lane][4 * g];
            f32x4 p2 = *(const f32x4*)&ldsO[2][wq][lane][4 * g];
            float e0 = (o_acc[4 * g + 0] + p0[0] + p1[0] + p2[0]) * inv;
            float e1 = (o_acc[4 * g + 1] + p0[1] + p1[1] + p2[1]) * inv;
            float e2 = (o_acc[4 * g + 2] + p0[2] + p1[2] + p2[2]) * inv;
            float e3 = (o_acc[4 * g + 3] + p0[3] + p1[3] + p2[3]) * inv;
            uint2 wv;
            wv.x = cvt_pk(e0, e1);
            wv.y = cvt_pk(e2, e3);
            *(uint2*)(orow + 8 * g) = wv;
        }
    }
}

// ---------------- Kernel 5: proj GEMM. out[b][o][n] = wproj[o][c] * att[c][n] + bias --
// Tile 64o x 64n, grid (64,4,2) = 512 blocks, 4 waves (2x2), wave 32o x 32n.
__global__ __launch_bounds__(256) void proj_gemm_kernel(const bf16* __restrict__ attT,
                                                        const bf16* __restrict__ w,
                                                        const float* __restrict__ bias,
                                                        float* __restrict__ out) {
    int b = blockIdx.z;
    int nb = blockIdx.x * 64, ob = blockIdx.y * 64;
    int t = threadIdx.x, wid = t >> 6, lane = t & 63;
    int l15 = lane & 15, g = lane >> 4;
    int wr = wid >> 1, wc = wid & 1;
    const bf16* arow = w + (size_t)(ob + wr * 32 + l15) * 256 + g * 8;
    const bf16* brow = attT + ((size_t)b * 4096 + nb + wc * 32 + l15) * 256 + g * 8;
    f32x4 acc[2][2] = {};
    for (int k0 = 0; k0 < 256; k0 += 32) {
        bf16x8 a[2], bb[2];
#pragma unroll
        for (int rt = 0; rt < 2; rt++) a[rt] = *(const bf16x8*)(arow + rt * 16 * 256 + k0);
#pragma unroll
        for (int cg = 0; cg < 2; cg++) bb[cg] = *(const bf16x8*)(brow + cg * 16 * 256 + k0);
#pragma unroll
        for (int rt = 0; rt < 2; rt++)
#pragma unroll
            for (int cg = 0; cg < 2; cg++)
                acc[rt][cg] = mfma16(a[rt], bb[cg], acc[rt][cg]);
    }
#pragma unroll
    for (int rt = 0; rt < 2; rt++)
#pragma unroll
        for (int cg = 0; cg < 2; cg++)
#pragma unroll
            for (int i = 0; i < 4; i++) {
                int o = ob + wr * 32 + rt * 16 + g * 4 + i;
                int n = nb + wc * 32 + cg * 16 + l15;
                out[((size_t)b * 256 + o) * 4096 + n] = acc[rt][cg][i] + bias[o];
            }
}

// ---------------- launch --------------------------------------------------------------
extern "C" void kernel_launch(void* const* d_in, const int* in_sizes, int n_in,
                              void* d_out, int out_size, void* d_ws, size_t ws_size,
                              hipStream_t stream) {
    const float* x      = (const float*)d_in[0];
    const float* qkv_w  = (const float*)d_in[1];
    const float* proj_w = (const float*)d_in[2];
    const float* proj_b = (const float*)d_in[3];
    float* out = (float*)d_out;

    char* ws = (char*)d_ws;
    bf16* xT    = (bf16*)(ws);                    // 4,194,304 B
    bf16* wqkv  = (bf16*)(ws + 4194304);          //   393,216 B
    bf16* wproj = (bf16*)(ws + 4587520);          //   131,072 B
    bf16* Qb    = (bf16*)(ws + 4718592);          // 4,194,304 B
    bf16* Kp    = (bf16*)(ws + 8912896);          // 4,194,304 B (fragment-packed)
    bf16* Vp    = (bf16*)(ws + 13107200);         // 4,194,304 B (fragment-packed)
    bf16* attT  = (bf16*)(ws + 17301504);         // 4,194,304 B -> end 21,495,808

    prep_w_kernel<<<1024, 256, 0, stream>>>(qkv_w, proj_w, wqkv, wproj);
    transpose_x_kernel<<<dim3(64, 4, 2), 256, 0, stream>>>(x, xT);
    qkv_gemm_kernel<<<dim3(64, 6, 2), 256, 0, stream>>>(xT, wqkv, Qb, Kp, Vp);
    attn_kernel<<<1024, 512, 0, stream>>>(Qb, Kp, Vp, attT);
    proj_gemm_kernel<<<dim3(64, 4, 2), 256, 0, stream>>>(attT, wproj, proj_b, out);
}

// Round 7
// 96.480 us; speedup vs baseline: 4.3649x; 4.3649x over previous
//
#include <hip/hip_runtime.h>
#include <hip/hip_bf16.h>

typedef __bf16 bf16;
typedef __bf16 bf16x8 __attribute__((ext_vector_type(8)));
typedef float f32x4 __attribute__((ext_vector_type(4)));
typedef float f32x16 __attribute__((ext_vector_type(16)));
typedef unsigned int u32x4 __attribute__((ext_vector_type(4)));

#define EXP2(x) __builtin_amdgcn_exp2f(x)

static __device__ __forceinline__ f32x4 mfma16(bf16x8 a, bf16x8 b, f32x4 c) {
    return __builtin_amdgcn_mfma_f32_16x16x32_bf16(a, b, c, 0, 0, 0);
}
static __device__ __forceinline__ f32x16 mfma32(bf16x8 a, bf16x8 b, f32x16 c) {
    return __builtin_amdgcn_mfma_f32_32x32x16_bf16(a, b, c, 0, 0, 0);
}
static __device__ __forceinline__ unsigned cvt_pk(float lo, float hi) {
    unsigned r;
    asm("v_cvt_pk_bf16_f32 %0, %1, %2" : "=v"(r) : "v"(lo), "v"(hi));
    return r;
}
static __device__ __forceinline__ void perm32swap(unsigned &a, unsigned &b) {
    asm("v_permlane32_swap_b32 %0, %1" : "+v"(a), "+v"(b));
}

// ---------------- Kernel 1: weight convert (+ fold softmax scale*log2e into Q rows) ----
__global__ __launch_bounds__(256) void prep_w_kernel(const float* __restrict__ qkv_w,
                                                     const float* __restrict__ proj_w,
                                                     bf16* __restrict__ wqkv,
                                                     bf16* __restrict__ wproj) {
    int idx = blockIdx.x * 256 + threadIdx.x;
    const float QSCALE = 0.17677669529663689f * 1.4426950408889634f; // hd^-0.5 * log2(e)
    if (idx < 768 * 256) {
        float v = qkv_w[idx];
        if (idx < 256 * 256) v *= QSCALE;   // rows o<256 are the Q projection
        wqkv[idx] = (bf16)v;
    } else {
        int j = idx - 768 * 256;
        wproj[j] = (bf16)proj_w[j];
    }
}

// ---------------- Kernel 2: x [2][256][4096] f32 -> xT [2][4096][256] bf16 ------------
// 64c x 64n tile; f32x4 coalesced loads, LDS transpose, bf16x8 16B stores.
__global__ __launch_bounds__(256) void transpose_x_kernel(const float* __restrict__ x,
                                                          bf16* __restrict__ xT) {
    __shared__ float tile[64][68];
    int b = blockIdx.z, cb = blockIdx.y * 64, nb = blockIdx.x * 64;
    int t = threadIdx.x;
    int j = t & 15, rc = t >> 4;     // load: rows c = rc+16i, cols n = j*4..j*4+3
    const float* src = x + ((size_t)b * 256 + cb) * 4096 + nb;
#pragma unroll
    for (int i = 0; i < 4; i++) {
        f32x4 v = *(const f32x4*)(src + (size_t)(rc + i * 16) * 4096 + j * 4);
        *(f32x4*)&tile[rc + i * 16][j * 4] = v;
    }
    __syncthreads();
    int n = t >> 2;                  // write: row n, c-octet (t&3) + 4i
    bf16* dst = xT + ((size_t)b * 4096 + nb + n) * 256 + cb;
#pragma unroll
    for (int i = 0; i < 2; i++) {
        int c0 = ((t & 3) + i * 4) * 8;
        bf16x8 v;
#pragma unroll
        for (int jj = 0; jj < 8; jj++) v[jj] = (bf16)tile[c0 + jj][n];
        *(bf16x8*)(dst + c0) = v;
    }
}

// ---------------- Kernel 3: QKV GEMM.  D[n][o] = xT[n][c] * wqkv[o][c]^T --------------
// Tile 64n x 128o, 4 waves (2x2), wave 32n x 64o. Q written [bh][n][32];
// K,V written MFMA-FRAGMENT-PACKED: Kp/Vp [bh][kt][which][lane][8].
__global__ __launch_bounds__(256) void qkv_gemm_kernel(const bf16* __restrict__ xT,
                                                       const bf16* __restrict__ w,
                                                       bf16* __restrict__ Q,
                                                       bf16* __restrict__ Kp,
                                                       bf16* __restrict__ Vp) {
    int b = blockIdx.z;
    int nb = blockIdx.x * 64, ob = blockIdx.y * 128;
    int t = threadIdx.x, wid = t >> 6, lane = t & 63;
    int l15 = lane & 15, g = lane >> 4;
    int wr = wid >> 1, wc = wid & 1;
    const bf16* xrow = xT + ((size_t)b * 4096 + nb + wr * 32 + l15) * 256 + g * 8;
    const bf16* wrow = w + (size_t)(ob + wc * 64 + l15) * 256 + g * 8;
    f32x4 acc[2][4] = {};
    for (int k0 = 0; k0 < 256; k0 += 32) {
        bf16x8 a[2], bb[4];
#pragma unroll
        for (int rt = 0; rt < 2; rt++) a[rt] = *(const bf16x8*)(xrow + rt * 16 * 256 + k0);
#pragma unroll
        for (int cg = 0; cg < 4; cg++) bb[cg] = *(const bf16x8*)(wrow + cg * 16 * 256 + k0);
#pragma unroll
        for (int rt = 0; rt < 2; rt++)
#pragma unroll
            for (int cg = 0; cg < 4; cg++)
                acc[rt][cg] = mfma16(a[rt], bb[cg], acc[rt][cg]);
    }
#pragma unroll
    for (int rt = 0; rt < 2; rt++) {
#pragma unroll
        for (int cg = 0; cg < 4; cg++) {
            int o = ob + wc * 64 + cg * 16 + l15;
            int tsel = o >> 8;           // 0=Q 1=K 2=V
            int h = (o >> 5) & 7;
            int d = o & 31;
            int n0 = nb + wr * 32 + rt * 16 + g * 4;
            size_t bhbase = ((size_t)b * 8 + h) * 131072;
            if (tsel == 0) {
#pragma unroll
                for (int i = 0; i < 4; i++)
                    Q[(((size_t)b * 8 + h) * 4096 + n0 + i) * 32 + d] = (bf16)acc[rt][cg][i];
            } else if (tsel == 1) {
                // K fragment pack: rows n, elems d. which = d>>4, hi2 = (d>>3)&1
                int kt = n0 >> 5;
                int which = d >> 4, hi2 = (d >> 3) & 1, j = d & 7;
                size_t base = bhbase + (size_t)(((kt * 2 + which) * 64 + hi2 * 32) * 8 + j);
#pragma unroll
                for (int i = 0; i < 4; i++) {
                    int r5 = (n0 + i) & 31;
                    Kp[base + r5 * 8] = (bf16)acc[rt][cg][i];
                }
            } else {
                // V^T fragment pack: rows d, elems k (=n). which = kk>>4, hi2 = (kk>>3)&1
                int kt = n0 >> 5, kk0 = n0 & 31;
                int which = kk0 >> 4, hi2 = (kk0 >> 3) & 1, j0 = kk0 & 7;
                unsigned p0 = cvt_pk(acc[rt][cg][0], acc[rt][cg][1]);
                unsigned p1 = cvt_pk(acc[rt][cg][2], acc[rt][cg][3]);
                uint2 wv; wv.x = p0; wv.y = p1;
                *(uint2*)(Vp + bhbase + (size_t)(((kt * 2 + which) * 64 + hi2 * 32 + d) * 8 + j0)) = wv;
            }
        }
    }
}

// ---------------- Kernel 4: flash attention, packed + XCD-swizzled + k-split 4 --------
// 1-D grid of 1024 blocks: bh = (w&7)+8*((w>>3)&1) (XCD-local), qblk = w>>4 (0..63).
// 512 thr = 8 waves: (z = wid>>1 in 0..3, wq = wid&1). Per wave: 32 q-rows, quarter
// k-range (1024 k), KVBLK=32, all loads base+lane*16B (fragment-packed).
// Fixed-base softmax. l = lane-local VALU sum (hi-pair rows partition k; one
// shfl_xor(32) after the loop). NO rs-MFMA, NO double-prefetch -> low regs;
// launch_bounds(512,6) caps ~85 regs = 6 waves/SIMD = 3 blocks/CU resident.
#define PACK(stv, B, OUT) {                                  \
    unsigned _x01 = cvt_pk(stv[B + 0], stv[B + 1]);          \
    unsigned _x23 = cvt_pk(stv[B + 2], stv[B + 3]);          \
    unsigned _y01 = cvt_pk(stv[B + 4], stv[B + 5]);          \
    unsigned _y23 = cvt_pk(stv[B + 6], stv[B + 7]);          \
    perm32swap(_x01, _y01);                                  \
    perm32swap(_x23, _y23);                                  \
    u32x4 _w = {_x01, _x23, _y01, _y23};                     \
    OUT = __builtin_bit_cast(bf16x8, _w); }

__global__ __launch_bounds__(512, 6) void attn_kernel(const bf16* __restrict__ Q,
                                                      const bf16* __restrict__ Kp,
                                                      const bf16* __restrict__ Vp,
                                                      bf16* __restrict__ attT) {
    __shared__ __align__(16) float ldsO[3][2][64][20];   // ~30 KB
    __shared__ float ldsL[3][2][32];

    const int w = blockIdx.x;
    const int bh = (w & 7) + 8 * ((w >> 3) & 1);   // XCD w&7 -> bh {w&7, w&7+8}
    const int qblk = w >> 4;                       // 0..63
    const int t = threadIdx.x;
    const int wid = t >> 6, lane = t & 63;
    const int z = wid >> 1, wq = wid & 1;          // z: k-quarter, wq: q-subtile
    const int l31 = lane & 31, hi = lane >> 5;
    const int q0 = qblk * 64 + wq * 32;

    const bf16* __restrict__ Qb = Q + (size_t)bh * 4096 * 32;
    const bf16* kptr = Kp + (size_t)bh * 131072 + (size_t)z * 32768 + lane * 8;
    const bf16* vptr = Vp + (size_t)bh * 131072 + (size_t)z * 32768 + lane * 8;

    // Q B-frags (col = q = l31), elements d = ks*16 + hi*8 + j
    bf16x8 qf0 = *(const bf16x8*)(Qb + (size_t)(q0 + l31) * 32 + hi * 8);
    bf16x8 qf1 = *(const bf16x8*)(Qb + (size_t)(q0 + l31) * 32 + 16 + hi * 8);

    const f32x16 ZERO16 = {};
    f32x16 o_acc = {};
    float lpart = 0.f;

    for (int it = 0; it < 32; ++it) {
        bf16x8 kf0 = *(const bf16x8*)(kptr);
        bf16x8 kf1 = *(const bf16x8*)(kptr + 512);
        bf16x8 vf0 = *(const bf16x8*)(vptr);
        bf16x8 vf1 = *(const bf16x8*)(vptr + 512);
        kptr += 1024; vptr += 1024;

        f32x16 st = mfma32(kf0, qf0, ZERO16);
        st = mfma32(kf1, qf1, st);

        // P = exp2(S)  (fixed base; |S| small, bf16 exp range = f32's)
#pragma unroll
        for (int r = 0; r < 16; r++) st[r] = EXP2(st[r]);

        // l partial: this lane's 16 k-rows (hi-partner holds the other 16)
        float s0 = 0.f, s1 = 0.f;
#pragma unroll
        for (int r = 0; r < 8; r++) { s0 += st[r]; s1 += st[r + 8]; }
        lpart += s0 + s1;

        bf16x8 pb0, pb1;
        PACK(st, 0, pb0);
        PACK(st, 8, pb1);

        __builtin_amdgcn_s_setprio(1);
        o_acc = mfma32(vf0, pb0, o_acc);     // O^T += V^T P
        o_acc = mfma32(vf1, pb1, o_acc);
        __builtin_amdgcn_s_setprio(0);
    }

    lpart += __shfl_xor(lpart, 32);          // full row-sum for this z-quarter

    // ---- combine 4 k-quarter partials via LDS, write attT [b][n][256] ----
    if (z != 0) {
#pragma unroll
        for (int g = 0; g < 4; g++) {
            f32x4 wv = {o_acc[4 * g + 0], o_acc[4 * g + 1], o_acc[4 * g + 2], o_acc[4 * g + 3]};
            *(f32x4*)&ldsO[z - 1][wq][lane][4 * g] = wv;
        }
        if (hi == 0) ldsL[z - 1][wq][l31] = lpart;
    }
    __syncthreads();
    if (z == 0) {
        float lsum = lpart + ldsL[0][wq][l31] + ldsL[1][wq][l31] + ldsL[2][wq][l31];
        float inv = __builtin_amdgcn_rcpf(lsum);
        const int b = bh >> 3, h = bh & 7;
        bf16* orow = attT + ((size_t)b * 4096 + q0 + l31) * 256 + h * 32 + 4 * hi;
#pragma unroll
        for (int g = 0; g < 4; g++) {
            f32x4 p0 = *(const f32x4*)&ldsO[0][wq][lane][4 * g];
            f32x4 p1 = *(const f32x4*)&ldsO[1][wq][lane][4 * g];
            f32x4 p2 = *(const f32x4*)&ldsO[2][wq][lane][4 * g];
            float e0 = (o_acc[4 * g + 0] + p0[0] + p1[0] + p2[0]) * inv;
            float e1 = (o_acc[4 * g + 1] + p0[1] + p1[1] + p2[1]) * inv;
            float e2 = (o_acc[4 * g + 2] + p0[2] + p1[2] + p2[2]) * inv;
            float e3 = (o_acc[4 * g + 3] + p0[3] + p1[3] + p2[3]) * inv;
            uint2 wv;
            wv.x = cvt_pk(e0, e1);
            wv.y = cvt_pk(e2, e3);
            *(uint2*)(orow + 8 * g) = wv;
        }
    }
}

// ---------------- Kernel 5: proj GEMM. out[b][o][n] = wproj[o][c] * att[c][n] + bias --
// Tile 64o x 64n, grid (64,4,2) = 512 blocks, 4 waves (2x2), wave 32o x 32n.
__global__ __launch_bounds__(256) void proj_gemm_kernel(const bf16* __restrict__ attT,
                                                        const bf16* __restrict__ w,
                                                        const float* __restrict__ bias,
                                                        float* __restrict__ out) {
    int b = blockIdx.z;
    int nb = blockIdx.x * 64, ob = blockIdx.y * 64;
    int t = threadIdx.x, wid = t >> 6, lane = t & 63;
    int l15 = lane & 15, g = lane >> 4;
    int wr = wid >> 1, wc = wid & 1;
    const bf16* arow = w + (size_t)(ob + wr * 32 + l15) * 256 + g * 8;
    const bf16* brow = attT + ((size_t)b * 4096 + nb + wc * 32 + l15) * 256 + g * 8;
    f32x4 acc[2][2] = {};
    for (int k0 = 0; k0 < 256; k0 += 32) {
        bf16x8 a[2], bb[2];
#pragma unroll
        for (int rt = 0; rt < 2; rt++) a[rt] = *(const bf16x8*)(arow + rt * 16 * 256 + k0);
#pragma unroll
        for (int cg = 0; cg < 2; cg++) bb[cg] = *(const bf16x8*)(brow + cg * 16 * 256 + k0);
#pragma unroll
        for (int rt = 0; rt < 2; rt++)
#pragma unroll
            for (int cg = 0; cg < 2; cg++)
                acc[rt][cg] = mfma16(a[rt], bb[cg], acc[rt][cg]);
    }
#pragma unroll
    for (int rt = 0; rt < 2; rt++)
#pragma unroll
        for (int cg = 0; cg < 2; cg++)
#pragma unroll
            for (int i = 0; i < 4; i++) {
                int o = ob + wr * 32 + rt * 16 + g * 4 + i;
                int n = nb + wc * 32 + cg * 16 + l15;
                out[((size_t)b * 256 + o) * 4096 + n] = acc[rt][cg][i] + bias[o];
            }
}

// ---------------- launch --------------------------------------------------------------
extern "C" void kernel_launch(void* const* d_in, const int* in_sizes, int n_in,
                              void* d_out, int out_size, void* d_ws, size_t ws_size,
                              hipStream_t stream) {
    const float* x      = (const float*)d_in[0];
    const float* qkv_w  = (const float*)d_in[1];
    const float* proj_w = (const float*)d_in[2];
    const float* proj_b = (const float*)d_in[3];
    float* out = (float*)d_out;

    char* ws = (char*)d_ws;
    bf16* xT    = (bf16*)(ws);                    // 4,194,304 B
    bf16* wqkv  = (bf16*)(ws + 4194304);          //   393,216 B
    bf16* wproj = (bf16*)(ws + 4587520);          //   131,072 B
    bf16* Qb    = (bf16*)(ws + 4718592);          // 4,194,304 B
    bf16* Kp    = (bf16*)(ws + 8912896);          // 4,194,304 B (fragment-packed)
    bf16* Vp    = (bf16*)(ws + 13107200);         // 4,194,304 B (fragment-packed)
    bf16* attT  = (bf16*)(ws + 17301504);         // 4,194,304 B -> end 21,495,808

    prep_w_kernel<<<1024, 256, 0, stream>>>(qkv_w, proj_w, wqkv, wproj);
    transpose_x_kernel<<<dim3(64, 4, 2), 256, 0, stream>>>(x, xT);
    qkv_gemm_kernel<<<dim3(64, 6, 2), 256, 0, stream>>>(xT, wqkv, Qb, Kp, Vp);
    attn_kernel<<<1024, 512, 0, stream>>>(Qb, Kp, Vp, attT);
    proj_gemm_kernel<<<dim3(64, 4, 2), 256, 0, stream>>>(attT, wproj, proj_b, out);
}